// Round 1
// baseline (810.126 us; speedup 1.0000x reference)
//
#include <hip/hip_runtime.h>

#define HH 256
#define WW 256
#define NB 64
#define NPIX (NB * HH * WW)   // 4,194,304
#define EPSF 1e-12f
#define N_ITER 10

// ---------------------------------------------------------------------------
// Setup: g2x/g2y (centered diffs of y, boundary diffs from x), zero u and p.
// ---------------------------------------------------------------------------
__global__ __launch_bounds__(256) void setup_kernel(
    const float* __restrict__ x, const float* __restrict__ y,
    float* __restrict__ g2x, float* __restrict__ g2y,
    float* __restrict__ u1, float* __restrict__ u2,
    float* __restrict__ p11, float* __restrict__ p12,
    float* __restrict__ p21, float* __restrict__ p22)
{
    int idx = blockIdx.x * blockDim.x + threadIdx.x;
    if (idx >= NPIX) return;
    int j = idx & (WW - 1);
    int i = (idx >> 8) & (HH - 1);

    float gx, gy;
    if (j == 0)            gx = 0.5f * (x[idx + 1]  - x[idx]);
    else if (j == WW - 1)  gx = 0.5f * (x[idx]      - x[idx - 1]);
    else                   gx = 0.5f * (y[idx + 1]  - y[idx - 1]);

    if (i == 0)            gy = 0.5f * (x[idx + WW] - x[idx]);
    else if (i == HH - 1)  gy = 0.5f * (x[idx]      - x[idx - WW]);
    else                   gy = 0.5f * (y[idx + WW] - y[idx - WW]);

    g2x[idx] = gx;  g2y[idx] = gy;
    u1[idx] = 0.f;  u2[idx] = 0.f;
    p11[idx] = 0.f; p12[idx] = 0.f;
    p21[idx] = 0.f; p22[idx] = 0.f;
}

// ---------------------------------------------------------------------------
// u-update: thresholding step (v) + ts * divergence(p)  [backward diffs]
//   div_x[0]=p[0]; div_x[j]=p[j]-p[j-1]; div_x[W-1]=-p[W-2]  (and same in y)
// ---------------------------------------------------------------------------
__global__ __launch_bounds__(256) void u_kernel(
    const float* __restrict__ x, const float* __restrict__ y,
    const float* __restrict__ g2x, const float* __restrict__ g2y,
    float* __restrict__ u1, float* __restrict__ u2,
    const float* __restrict__ p11, const float* __restrict__ p12,
    const float* __restrict__ p21, const float* __restrict__ p22,
    const float* __restrict__ tp, const float* __restrict__ lp,
    const float* __restrict__ ap)
{
    int idx = blockIdx.x * blockDim.x + threadIdx.x;
    if (idx >= NPIX) return;
    float ts  = tp[0];
    float l_t = lp[0] * ts;

    int j = idx & (WW - 1);
    int i = (idx >> 8) & (HH - 1);

    float gx = g2x[idx], gy = g2y[idx];
    float grad = gx * gx + gy * gy + EPSF;
    float u1c = u1[idx], u2c = u2[idx];
    float rho = (y[idx] - x[idx]) + gx * u1c + gy * u2c + EPSF;

    float thresh = l_t * grad;
    float v1, v2;
    if (rho < -thresh)        { v1 =  l_t * gx;  v2 =  l_t * gy; }
    else if (rho > thresh)    { v1 = -l_t * gx;  v2 = -l_t * gy; }
    else if (grad > EPSF)     { float s = -rho / grad; v1 = s * gx; v2 = s * gy; }
    else                      { v1 = 0.f; v2 = 0.f; }

    // divergence of (p11,p12) and (p21,p22)
    float p11c = (j < WW - 1) ? p11[idx]      : 0.f;
    float p11l = (j > 0)      ? p11[idx - 1]  : 0.f;
    float p12c = (i < HH - 1) ? p12[idx]      : 0.f;
    float p12u = (i > 0)      ? p12[idx - WW] : 0.f;
    float div1 = (p11c - p11l) + (p12c - p12u);

    float p21c = (j < WW - 1) ? p21[idx]      : 0.f;
    float p21l = (j > 0)      ? p21[idx - 1]  : 0.f;
    float p22c = (i < HH - 1) ? p22[idx]      : 0.f;
    float p22u = (i > 0)      ? p22[idx - WW] : 0.f;
    float div2 = (p21c - p21l) + (p22c - p22u);

    u1[idx] = (v1 + u1c) + ts * div1;
    u2[idx] = (v2 + u2c) + ts * div2;
}

// ---------------------------------------------------------------------------
// p-update: forward diffs of u (right/down, 0 on last col/row), normalize.
// ---------------------------------------------------------------------------
__global__ __launch_bounds__(256) void p_kernel(
    const float* __restrict__ u1, const float* __restrict__ u2,
    float* __restrict__ p11, float* __restrict__ p12,
    float* __restrict__ p21, float* __restrict__ p22,
    const float* __restrict__ tp, const float* __restrict__ ap)
{
    int idx = blockIdx.x * blockDim.x + threadIdx.x;
    if (idx >= NPIX) return;
    float ts   = tp[0];
    float taut = ap[0] / ts;

    int j = idx & (WW - 1);
    int i = (idx >> 8) & (HH - 1);

    float u1c = u1[idx], u2c = u2[idx];
    float u1x = (j < WW - 1) ? u1[idx + 1]  - u1c : 0.f;
    float u1y = (i < HH - 1) ? u1[idx + WW] - u1c : 0.f;
    float u2x = (j < WW - 1) ? u2[idx + 1]  - u2c : 0.f;
    float u2y = (i < HH - 1) ? u2[idx + WW] - u2c : 0.f;

    float n1 = sqrtf(u1x * u1x + u1y * u1y + EPSF);
    float n2 = sqrtf(u2x * u2x + u2y * u2y + EPSF);
    float d1 = 1.f + taut * n1;
    float d2 = 1.f + taut * n2;

    p11[idx] = (p11[idx] + taut * u1x) / d1;
    p12[idx] = (p12[idx] + taut * u1y) / d1;
    p21[idx] = (p21[idx] + taut * u2x) / d2;
    p22[idx] = (p22[idx] + taut * u2y) / d2;
}

// ---------------------------------------------------------------------------
extern "C" void kernel_launch(void* const* d_in, const int* in_sizes, int n_in,
                              void* d_out, int out_size, void* d_ws, size_t ws_size,
                              hipStream_t stream) {
    const float* x = (const float*)d_in[0];
    const float* y = (const float*)d_in[1];
    // d_in[2..7] are the fixed conv stencils (values baked into the kernels)
    const float* t = (const float*)d_in[8];
    const float* l = (const float*)d_in[9];
    const float* a = (const float*)d_in[10];

    float* u1 = (float*)d_out;          // output 0
    float* u2 = u1 + NPIX;              // output 1

    float* ws  = (float*)d_ws;          // needs 6 * 16 MiB = 96 MiB
    float* g2x = ws + (size_t)0 * NPIX;
    float* g2y = ws + (size_t)1 * NPIX;
    float* p11 = ws + (size_t)2 * NPIX;
    float* p12 = ws + (size_t)3 * NPIX;
    float* p21 = ws + (size_t)4 * NPIX;
    float* p22 = ws + (size_t)5 * NPIX;

    dim3 block(256);
    dim3 grid(NPIX / 256);

    setup_kernel<<<grid, block, 0, stream>>>(x, y, g2x, g2y, u1, u2,
                                             p11, p12, p21, p22);
    for (int it = 0; it < N_ITER; ++it) {
        u_kernel<<<grid, block, 0, stream>>>(x, y, g2x, g2y, u1, u2,
                                             p11, p12, p21, p22, t, l, a);
        p_kernel<<<grid, block, 0, stream>>>(u1, u2, p11, p12, p21, p22, t, a);
    }
}

// Round 2
// 725.941 us; speedup vs baseline: 1.1160x; 1.1160x over previous
//
#include <hip/hip_runtime.h>

#define HH 256
#define WW 256
#define NB 64
#define NPIX (NB * HH * WW)   // 4,194,304
#define EPSF 1e-12f

// Tile geometry: each block produces a 32(high) x 64(wide) interior tile,
// computing u_new on an extended 33 x 65 region (right/bottom +1 halo) in LDS.
#define TW 64
#define TH 32
#define EH (TH + 1)           // 33
#define LSTR 66               // LDS row stride (floats)
#define TILES_X (WW / TW)     // 4
#define TILES_Y (HH / TH)     // 8
#define NTILES (NB * TILES_X * TILES_Y)   // 2048

// ---------------------------------------------------------------------------
// TV-L1 u-update core: thresholding (v) + ts * divergence(p_old)
// ---------------------------------------------------------------------------
__device__ __forceinline__ void u_core(
    float gx, float gy, float rcv, float u1c, float u2c,
    float p11c, float p11l, float p12c, float p12u,
    float p21c, float p21l, float p22c, float p22u,
    float ts, float l_t, float& u1n, float& u2n)
{
    float grad = gx * gx + gy * gy + EPSF;
    float rho  = rcv + gx * u1c + gy * u2c + EPSF;
    float th   = l_t * grad;
    float v1, v2;
    if (rho < -th)      { v1 =  l_t * gx; v2 =  l_t * gy; }
    else if (rho > th)  { v1 = -l_t * gx; v2 = -l_t * gy; }
    else                { float s = -rho / grad; v1 = s * gx; v2 = s * gy; }
    // note: when gx=gy=0 (grad==EPSF, mask3 false in ref) s*gx == 0 anyway.
    float div1 = (p11c - p11l) + (p12c - p12u);
    float div2 = (p21c - p21l) + (p22c - p22u);
    u1n = v1 + u1c + ts * div1;
    u2n = v2 + u2c + ts * div2;
}

// Image gradients of y with boundary corrections from x; rho_c = y - x.
__device__ __forceinline__ void g_core(
    int idx, int gi, int gj,
    const float* __restrict__ x, const float* __restrict__ y,
    float& gx, float& gy, float& rcv)
{
    if (gj == 0)          gx = 0.5f * (x[idx + 1]  - x[idx]);
    else if (gj == WW-1)  gx = 0.5f * (x[idx]      - x[idx - 1]);
    else                  gx = 0.5f * (y[idx + 1]  - y[idx - 1]);
    if (gi == 0)          gy = 0.5f * (x[idx + WW] - x[idx]);
    else if (gi == HH-1)  gy = 0.5f * (x[idx]      - x[idx - WW]);
    else                  gy = 0.5f * (y[idx + WW] - y[idx - WW]);
    rcv = y[idx] - x[idx];
}

// ---------------------------------------------------------------------------
// Iteration 0 specialized: u_old = p_old = 0. Computes g2x/g2y/rc inline from
// x,y, stores them for later iterations, and does the fused u+p update.
// ---------------------------------------------------------------------------
__global__ __launch_bounds__(256) void fused0_kernel(
    const float* __restrict__ x, const float* __restrict__ y,
    float* __restrict__ g2x, float* __restrict__ g2y, float* __restrict__ rc,
    float* __restrict__ u1n, float* __restrict__ u2n,
    float* __restrict__ p11n, float* __restrict__ p12n,
    float* __restrict__ p21n, float* __restrict__ p22n,
    const float* __restrict__ tp, const float* __restrict__ lp,
    const float* __restrict__ ap)
{
    __shared__ float su1[EH][LSTR];
    __shared__ float su2[EH][LSTR];

    const float ts   = tp[0];
    const float l_t  = lp[0] * ts;
    const float taut = ap[0] / ts;

    const int tile = blockIdx.x;
    const int gj0  = (tile & (TILES_X - 1)) * TW;
    const int gi0  = ((tile >> 2) & (TILES_Y - 1)) * TH;
    const int base = (tile >> 5) * (HH * WW);

    const int tx = threadIdx.x & 63;
    const int ty = threadIdx.x >> 6;     // wave id, 0..3

    // Phase 1a: u_new on rows 0..32, cols 0..63 of extended tile
    for (int r = ty; r < EH; r += 4) {
        int gi = gi0 + r;
        if (gi < HH) {
            int gj = gj0 + tx;
            int idx = base + gi * WW + gj;
            float gx, gy, rcv;
            g_core(idx, gi, gj, x, y, gx, gy, rcv);
            float u1v, u2v;
            u_core(gx, gy, rcv, 0.f, 0.f, 0,0,0,0, 0,0,0,0, ts, l_t, u1v, u2v);
            su1[r][tx] = u1v;
            su2[r][tx] = u2v;
            if (r < TH) {  // interior rows: persist g-fields for iters 1..9
                g2x[idx] = gx; g2y[idx] = gy; rc[idx] = rcv;
            }
        }
    }
    // Phase 1b: extended right column (col 64), if inside image
    if (gj0 + TW < WW && threadIdx.x < EH) {
        int r = threadIdx.x;
        int gi = gi0 + r;
        if (gi < HH) {
            int gj = gj0 + TW;
            int idx = base + gi * WW + gj;
            float gx, gy, rcv;
            g_core(idx, gi, gj, x, y, gx, gy, rcv);
            float u1v, u2v;
            u_core(gx, gy, rcv, 0.f, 0.f, 0,0,0,0, 0,0,0,0, ts, l_t, u1v, u2v);
            su1[r][TW] = u1v;
            su2[r][TW] = u2v;
        }
    }
    __syncthreads();

    // Phase 2: p-update on interior (p_old = 0), write u_new + p_new
    for (int q = threadIdx.x; q < TH * TW; q += 256) {
        int r = q >> 6, c = q & 63;
        int gi = gi0 + r, gj = gj0 + c;
        int idx = base + gi * WW + gj;
        float u1c = su1[r][c], u2c = su2[r][c];
        float u1x = (gj < WW-1) ? su1[r][c+1] - u1c : 0.f;
        float u1y = (gi < HH-1) ? su1[r+1][c] - u1c : 0.f;
        float u2x = (gj < WW-1) ? su2[r][c+1] - u2c : 0.f;
        float u2y = (gi < HH-1) ? su2[r+1][c] - u2c : 0.f;
        float n1 = sqrtf(u1x*u1x + u1y*u1y + EPSF);
        float n2 = sqrtf(u2x*u2x + u2y*u2y + EPSF);
        float d1 = 1.f + taut * n1;
        float d2 = 1.f + taut * n2;
        p11n[idx] = (taut * u1x) / d1;
        p12n[idx] = (taut * u1y) / d1;
        p21n[idx] = (taut * u2x) / d2;
        p22n[idx] = (taut * u2y) / d2;
        u1n[idx] = u1c;
        u2n[idx] = u2c;
    }
}

// ---------------------------------------------------------------------------
// Fused u+p iteration: reads state set "o", writes state set "n" (ping-pong).
// ---------------------------------------------------------------------------
__global__ __launch_bounds__(256) void fused_kernel(
    const float* __restrict__ g2x, const float* __restrict__ g2y,
    const float* __restrict__ rc,
    const float* __restrict__ u1o, const float* __restrict__ u2o,
    const float* __restrict__ p11o, const float* __restrict__ p12o,
    const float* __restrict__ p21o, const float* __restrict__ p22o,
    float* __restrict__ u1n, float* __restrict__ u2n,
    float* __restrict__ p11n, float* __restrict__ p12n,
    float* __restrict__ p21n, float* __restrict__ p22n,
    const float* __restrict__ tp, const float* __restrict__ lp,
    const float* __restrict__ ap)
{
    __shared__ float su1[EH][LSTR];
    __shared__ float su2[EH][LSTR];

    const float ts   = tp[0];
    const float l_t  = lp[0] * ts;
    const float taut = ap[0] / ts;

    const int tile = blockIdx.x;
    const int gj0  = (tile & (TILES_X - 1)) * TW;
    const int gi0  = ((tile >> 2) & (TILES_Y - 1)) * TH;
    const int base = (tile >> 5) * (HH * WW);

    const int tx = threadIdx.x & 63;
    const int ty = threadIdx.x >> 6;

    // Phase 1a: u_new on rows 0..32, cols 0..63 of extended tile
    for (int r = ty; r < EH; r += 4) {
        int gi = gi0 + r;
        if (gi < HH) {
            int gj = gj0 + tx;
            int idx = base + gi * WW + gj;
            float p11c = (gj < WW-1) ? p11o[idx]      : 0.f;
            float p11l = (gj > 0)    ? p11o[idx - 1]  : 0.f;
            float p12c = (gi < HH-1) ? p12o[idx]      : 0.f;
            float p12u = (gi > 0)    ? p12o[idx - WW] : 0.f;
            float p21c = (gj < WW-1) ? p21o[idx]      : 0.f;
            float p21l = (gj > 0)    ? p21o[idx - 1]  : 0.f;
            float p22c = (gi < HH-1) ? p22o[idx]      : 0.f;
            float p22u = (gi > 0)    ? p22o[idx - WW] : 0.f;
            float u1v, u2v;
            u_core(g2x[idx], g2y[idx], rc[idx], u1o[idx], u2o[idx],
                   p11c, p11l, p12c, p12u, p21c, p21l, p22c, p22u,
                   ts, l_t, u1v, u2v);
            su1[r][tx] = u1v;
            su2[r][tx] = u2v;
        }
    }
    // Phase 1b: extended right column (col 64)
    if (gj0 + TW < WW && threadIdx.x < EH) {
        int r = threadIdx.x;
        int gi = gi0 + r;
        if (gi < HH) {
            int gj = gj0 + TW;
            int idx = base + gi * WW + gj;
            float p11c = (gj < WW-1) ? p11o[idx]      : 0.f;
            float p11l =               p11o[idx - 1];          // gj>0 always here
            float p12c = (gi < HH-1) ? p12o[idx]      : 0.f;
            float p12u = (gi > 0)    ? p12o[idx - WW] : 0.f;
            float p21c = (gj < WW-1) ? p21o[idx]      : 0.f;
            float p21l =               p21o[idx - 1];
            float p22c = (gi < HH-1) ? p22o[idx]      : 0.f;
            float p22u = (gi > 0)    ? p22o[idx - WW] : 0.f;
            float u1v, u2v;
            u_core(g2x[idx], g2y[idx], rc[idx], u1o[idx], u2o[idx],
                   p11c, p11l, p12c, p12u, p21c, p21l, p22c, p22u,
                   ts, l_t, u1v, u2v);
            su1[r][TW] = u1v;
            su2[r][TW] = u2v;
        }
    }
    __syncthreads();

    // Phase 2: p-update on interior from LDS u_new; write u_new + p_new
    for (int q = threadIdx.x; q < TH * TW; q += 256) {
        int r = q >> 6, c = q & 63;
        int gi = gi0 + r, gj = gj0 + c;
        int idx = base + gi * WW + gj;
        float u1c = su1[r][c], u2c = su2[r][c];
        float u1x = (gj < WW-1) ? su1[r][c+1] - u1c : 0.f;
        float u1y = (gi < HH-1) ? su1[r+1][c] - u1c : 0.f;
        float u2x = (gj < WW-1) ? su2[r][c+1] - u2c : 0.f;
        float u2y = (gi < HH-1) ? su2[r+1][c] - u2c : 0.f;
        float n1 = sqrtf(u1x*u1x + u1y*u1y + EPSF);
        float n2 = sqrtf(u2x*u2x + u2y*u2y + EPSF);
        float d1 = 1.f + taut * n1;
        float d2 = 1.f + taut * n2;
        p11n[idx] = (p11o[idx] + taut * u1x) / d1;
        p12n[idx] = (p12o[idx] + taut * u1y) / d1;
        p21n[idx] = (p21o[idx] + taut * u2x) / d2;
        p22n[idx] = (p22o[idx] + taut * u2y) / d2;
        u1n[idx] = u1c;
        u2n[idx] = u2c;
    }
}

// ---------------------------------------------------------------------------
extern "C" void kernel_launch(void* const* d_in, const int* in_sizes, int n_in,
                              void* d_out, int out_size, void* d_ws, size_t ws_size,
                              hipStream_t stream) {
    const float* x = (const float*)d_in[0];
    const float* y = (const float*)d_in[1];
    const float* t = (const float*)d_in[8];
    const float* l = (const float*)d_in[9];
    const float* a = (const float*)d_in[10];

    // State set A: u in d_out (final result lands here after iter 9), p in ws.
    float* u1A = (float*)d_out;
    float* u2A = u1A + NPIX;

    float* ws   = (float*)d_ws;   // 13 fields x 16 MiB = 208 MiB
    float* g2x  = ws + (size_t) 0 * NPIX;
    float* g2y  = ws + (size_t) 1 * NPIX;
    float* rc   = ws + (size_t) 2 * NPIX;
    float* p11A = ws + (size_t) 3 * NPIX;
    float* p12A = ws + (size_t) 4 * NPIX;
    float* p21A = ws + (size_t) 5 * NPIX;
    float* p22A = ws + (size_t) 6 * NPIX;
    float* u1B  = ws + (size_t) 7 * NPIX;
    float* u2B  = ws + (size_t) 8 * NPIX;
    float* p11B = ws + (size_t) 9 * NPIX;
    float* p12B = ws + (size_t)10 * NPIX;
    float* p21B = ws + (size_t)11 * NPIX;
    float* p22B = ws + (size_t)12 * NPIX;

    dim3 block(256), grid(NTILES);

    // iter 0 (u=p=0) writes set B; iters 1..9 ping-pong; iter 9 writes set A.
    fused0_kernel<<<grid, block, 0, stream>>>(
        x, y, g2x, g2y, rc,
        u1B, u2B, p11B, p12B, p21B, p22B, t, l, a);

    for (int k = 1; k <= 9; ++k) {
        if (k & 1) {   // read B -> write A
            fused_kernel<<<grid, block, 0, stream>>>(
                g2x, g2y, rc,
                u1B, u2B, p11B, p12B, p21B, p22B,
                u1A, u2A, p11A, p12A, p21A, p22A, t, l, a);
        } else {       // read A -> write B
            fused_kernel<<<grid, block, 0, stream>>>(
                g2x, g2y, rc,
                u1A, u2A, p11A, p12A, p21A, p22A,
                u1B, u2B, p11B, p12B, p21B, p22B, t, l, a);
        }
    }
}

// Round 4
// 613.448 us; speedup vs baseline: 1.3206x; 1.1834x over previous
//
#include <hip/hip_runtime.h>

#define HH 256
#define WW 256
#define NB 64
#define NPIX (NB * HH * WW)      // 4,194,304 pixels
#define NF4  (NPIX / 4)          // 1,048,576 float4s
#define ROW4 (WW / 4)            // 64 float4s per image row
#define EPSF 1e-12f
#define NTHR 256
#define NBLK (NF4 / NTHR)        // 4096 blocks, 1 float4 per thread

__device__ __forceinline__ float4 ld4(const float* p, int f) {
    return ((const float4*)p)[f];
}
__device__ __forceinline__ void st4(float* p, int f, const float* v) {
    ((float4*)p)[f] = make_float4(v[0], v[1], v[2], v[3]);
}

// TV-L1 thresholding step.
__device__ __forceinline__ void thresh(
    float gx, float gy, float rho, float grad, float l_t,
    float& v1, float& v2)
{
    float th = l_t * grad;
    if (rho < -th)      { v1 =  l_t * gx; v2 =  l_t * gy; }
    else if (rho > th)  { v1 = -l_t * gx; v2 = -l_t * gy; }
    else                { float s = -rho / grad; v1 = s * gx; v2 = s * gy; }
}

// ---------------------------------------------------------------------------
// S: g2x/g2y/rc from x,y; iteration-0 u-update (u=0, p=0 -> u = v).
// ---------------------------------------------------------------------------
__global__ __launch_bounds__(NTHR) void s_kernel(
    const float* __restrict__ x, const float* __restrict__ y,
    float* __restrict__ g2x, float* __restrict__ g2y, float* __restrict__ rc,
    float* __restrict__ u1, float* __restrict__ u2,
    const float* __restrict__ tp, const float* __restrict__ lp)
{
    int f = blockIdx.x * NTHR + threadIdx.x;
    const float l_t = lp[0] * tp[0];

    int idx = f << 2;
    int i  = (idx >> 8) & 255;
    int j0 = idx & 255;

    float4 xc4 = ld4(x, f), yc4 = ld4(y, f);
    const float* xc = (const float*)&xc4;
    const float* yc = (const float*)&yc4;

    float4 a4, b4;                       // wave-uniform row branch
    if (i == 0)            { a4 = ld4(x, f + ROW4); b4 = xc4; }
    else if (i == HH - 1)  { a4 = xc4; b4 = ld4(x, f - ROW4); }
    else                   { a4 = ld4(y, f + ROW4); b4 = ld4(y, f - ROW4); }
    const float* aa = (const float*)&a4;
    const float* bb = (const float*)&b4;

    float yl = (j0 > 0)      ? y[idx - 1] : 0.f;
    float yr = (j0 < WW - 4) ? y[idx + 4] : 0.f;

    float gxo[4], gyo[4], rco[4], u1o[4], u2o[4];
    #pragma unroll
    for (int k = 0; k < 4; ++k) {
        int j = j0 + k;
        float gx;
        if (j == 0)            gx = 0.5f * (xc[1] - xc[0]);
        else if (j == WW - 1)  gx = 0.5f * (xc[3] - xc[2]);
        else {
            float ynext = (k < 3) ? yc[k + 1] : yr;
            float yprev = (k > 0) ? yc[k - 1] : yl;
            gx = 0.5f * (ynext - yprev);
        }
        float gy = 0.5f * (aa[k] - bb[k]);
        float rcv = yc[k] - xc[k];
        float grad = gx * gx + gy * gy + EPSF;
        float rho  = rcv + EPSF;
        float v1, v2;
        thresh(gx, gy, rho, grad, l_t, v1, v2);
        gxo[k] = gx; gyo[k] = gy; rco[k] = rcv;
        u1o[k] = v1; u2o[k] = v2;
    }
    st4(g2x, f, gxo); st4(g2y, f, gyo); st4(rc, f, rco);
    st4(u1, f, u1o);  st4(u2, f, u2o);
}

// ---------------------------------------------------------------------------
// A: u-update in place. Reads u (own), p (own + left/up halo).
// ---------------------------------------------------------------------------
__global__ __launch_bounds__(NTHR) void a_kernel(
    const float* __restrict__ g2x, const float* __restrict__ g2y,
    const float* __restrict__ rc,
    float* __restrict__ u1, float* __restrict__ u2,
    const float* __restrict__ p11, const float* __restrict__ p12,
    const float* __restrict__ p21, const float* __restrict__ p22,
    const float* __restrict__ tp, const float* __restrict__ lp)
{
    int f = blockIdx.x * NTHR + threadIdx.x;
    const float ts  = tp[0];
    const float l_t = lp[0] * ts;

    int idx = f << 2;
    int i  = (idx >> 8) & 255;
    int j0 = idx & 255;

    float4 gx4  = ld4(g2x, f), gy4 = ld4(g2y, f), rc4 = ld4(rc, f);
    float4 u1c4 = ld4(u1, f),  u2c4 = ld4(u2, f);
    float4 p11c4 = ld4(p11, f), p12c4 = ld4(p12, f);
    float4 p21c4 = ld4(p21, f), p22c4 = ld4(p22, f);
    float4 zero4 = make_float4(0.f, 0.f, 0.f, 0.f);
    float4 p12u4 = (i > 0) ? ld4(p12, f - ROW4) : zero4;
    float4 p22u4 = (i > 0) ? ld4(p22, f - ROW4) : zero4;

    const float* gx  = (const float*)&gx4;
    const float* gy  = (const float*)&gy4;
    const float* rcv = (const float*)&rc4;
    const float* u1c = (const float*)&u1c4;
    const float* u2c = (const float*)&u2c4;
    const float* c11 = (const float*)&p11c4;
    const float* c12 = (const float*)&p12c4;
    const float* c21 = (const float*)&p21c4;
    const float* c22 = (const float*)&p22c4;
    const float* up12 = (const float*)&p12u4;
    const float* up22 = (const float*)&p22u4;

    float p11l = (j0 > 0) ? p11[idx - 1] : 0.f;
    float p21l = (j0 > 0) ? p21[idx - 1] : 0.f;
    bool notBot = (i < HH - 1);

    float u1o[4], u2o[4];
    #pragma unroll
    for (int k = 0; k < 4; ++k) {
        int j = j0 + k;
        float t11 = (j < WW - 1) ? c11[k] : 0.f;
        float l11 = (k == 0) ? p11l : c11[k - 1];
        float t21 = (j < WW - 1) ? c21[k] : 0.f;
        float l21 = (k == 0) ? p21l : c21[k - 1];
        float t12 = notBot ? c12[k] : 0.f;
        float t22 = notBot ? c22[k] : 0.f;
        float div1 = (t11 - l11) + (t12 - up12[k]);
        float div2 = (t21 - l21) + (t22 - up22[k]);

        float grad = gx[k] * gx[k] + gy[k] * gy[k] + EPSF;
        float rho  = rcv[k] + gx[k] * u1c[k] + gy[k] * u2c[k] + EPSF;
        float v1, v2;
        thresh(gx[k], gy[k], rho, grad, l_t, v1, v2);
        u1o[k] = v1 + u1c[k] + ts * div1;
        u2o[k] = v2 + u2c[k] + ts * div2;
    }
    st4(u1, f, u1o); st4(u2, f, u2o);
}

// ---------------------------------------------------------------------------
// B: p-update in place. Reads p (own), u (own + right/down halo).
// ---------------------------------------------------------------------------
template <bool P0>
__global__ __launch_bounds__(NTHR) void b_kernel(
    const float* __restrict__ u1, const float* __restrict__ u2,
    float* __restrict__ p11, float* __restrict__ p12,
    float* __restrict__ p21, float* __restrict__ p22,
    const float* __restrict__ tp, const float* __restrict__ ap)
{
    int f = blockIdx.x * NTHR + threadIdx.x;
    const float taut = ap[0] / tp[0];

    int idx = f << 2;
    int i  = (idx >> 8) & 255;
    int j0 = idx & 255;

    float4 u1c4 = ld4(u1, f), u2c4 = ld4(u2, f);
    float4 zero4 = make_float4(0.f, 0.f, 0.f, 0.f);
    bool notBot = (i < HH - 1);
    float4 u1d4 = notBot ? ld4(u1, f + ROW4) : zero4;
    float4 u2d4 = notBot ? ld4(u2, f + ROW4) : zero4;
    float u1r = (j0 < WW - 4) ? u1[idx + 4] : 0.f;
    float u2r = (j0 < WW - 4) ? u2[idx + 4] : 0.f;

    float4 p11c4 = zero4, p12c4 = zero4, p21c4 = zero4, p22c4 = zero4;
    if (!P0) {
        p11c4 = ld4(p11, f); p12c4 = ld4(p12, f);
        p21c4 = ld4(p21, f); p22c4 = ld4(p22, f);
    }

    const float* u1c = (const float*)&u1c4;
    const float* u2c = (const float*)&u2c4;
    const float* u1d = (const float*)&u1d4;
    const float* u2d = (const float*)&u2d4;
    const float* c11 = (const float*)&p11c4;
    const float* c12 = (const float*)&p12c4;
    const float* c21 = (const float*)&p21c4;
    const float* c22 = (const float*)&p22c4;

    float o11[4], o12[4], o21[4], o22[4];
    #pragma unroll
    for (int k = 0; k < 4; ++k) {
        int j = j0 + k;
        float u1x = 0.f, u2x = 0.f;
        if (j < WW - 1) {
            float n1 = (k < 3) ? u1c[k + 1] : u1r;
            float n2 = (k < 3) ? u2c[k + 1] : u2r;
            u1x = n1 - u1c[k];
            u2x = n2 - u2c[k];
        }
        float u1y = notBot ? (u1d[k] - u1c[k]) : 0.f;
        float u2y = notBot ? (u2d[k] - u2c[k]) : 0.f;

        float n1 = sqrtf(u1x * u1x + u1y * u1y + EPSF);
        float n2 = sqrtf(u2x * u2x + u2y * u2y + EPSF);
        float r1 = 1.f / (1.f + taut * n1);
        float r2 = 1.f / (1.f + taut * n2);
        o11[k] = (c11[k] + taut * u1x) * r1;
        o12[k] = (c12[k] + taut * u1y) * r1;
        o21[k] = (c21[k] + taut * u2x) * r2;
        o22[k] = (c22[k] + taut * u2y) * r2;
    }
    st4(p11, f, o11); st4(p12, f, o12);
    st4(p21, f, o21); st4(p22, f, o22);
}

// ---------------------------------------------------------------------------
extern "C" void kernel_launch(void* const* d_in, const int* in_sizes, int n_in,
                              void* d_out, int out_size, void* d_ws, size_t ws_size,
                              hipStream_t stream) {
    const float* x = (const float*)d_in[0];
    const float* y = (const float*)d_in[1];
    const float* t = (const float*)d_in[8];
    const float* l = (const float*)d_in[9];
    const float* a = (const float*)d_in[10];

    float* u1 = (float*)d_out;
    float* u2 = u1 + NPIX;

    float* ws  = (float*)d_ws;   // 7 fields x 16 MiB = 117 MiB
    float* g2x = ws + (size_t)0 * NPIX;
    float* g2y = ws + (size_t)1 * NPIX;
    float* rc  = ws + (size_t)2 * NPIX;
    float* p11 = ws + (size_t)3 * NPIX;
    float* p12 = ws + (size_t)4 * NPIX;
    float* p21 = ws + (size_t)5 * NPIX;
    float* p22 = ws + (size_t)6 * NPIX;

    dim3 block(NTHR), grid(NBLK);

    // iteration 0
    s_kernel<<<grid, block, 0, stream>>>(x, y, g2x, g2y, rc, u1, u2, t, l);
    b_kernel<true><<<grid, block, 0, stream>>>(u1, u2, p11, p12, p21, p22, t, a);
    // iterations 1..8
    for (int it = 1; it <= 8; ++it) {
        a_kernel<<<grid, block, 0, stream>>>(g2x, g2y, rc, u1, u2,
                                             p11, p12, p21, p22, t, l);
        b_kernel<false><<<grid, block, 0, stream>>>(u1, u2, p11, p12, p21, p22, t, a);
    }
    // iteration 9: p-update is dead, only u-update matters
    a_kernel<<<grid, block, 0, stream>>>(g2x, g2y, rc, u1, u2,
                                         p11, p12, p21, p22, t, l);
}

// Round 5
// 470.689 us; speedup vs baseline: 1.7212x; 1.3033x over previous
//
#include <hip/hip_runtime.h>
#include <hip/hip_fp16.h>

#define HH 256
#define WW 256
#define NB 64
#define NPIX (NB * HH * WW)      // 4,194,304 pixels
#define NF4  (NPIX / 4)          // 1,048,576 groups of 4
#define ROW4 (WW / 4)            // 64 groups per image row
#define EPSF 1e-12f
#define NTHR 256
#define NBLK (NF4 / NTHR)        // 4096 blocks, 1 group per thread

__device__ __forceinline__ float4 ld4(const float* p, int f) {
    return ((const float4*)p)[f];
}
__device__ __forceinline__ void st4(float* p, int f, const float* v) {
    ((float4*)p)[f] = make_float4(v[0], v[1], v[2], v[3]);
}
// 4 halves as one 8-byte vector load/store, expanded to/from float
__device__ __forceinline__ void ld4h(const __half* p, int f, float* o) {
    float2 raw = ((const float2*)p)[f];
    __half2 h0 = *(__half2*)&raw.x;
    __half2 h1 = *(__half2*)&raw.y;
    float2 a = __half22float2(h0), b = __half22float2(h1);
    o[0] = a.x; o[1] = a.y; o[2] = b.x; o[3] = b.y;
}
__device__ __forceinline__ void st4h(__half* p, int f, const float* v) {
    __half2 h0 = __floats2half2_rn(v[0], v[1]);
    __half2 h1 = __floats2half2_rn(v[2], v[3]);
    float2 raw;
    raw.x = *(float*)&h0; raw.y = *(float*)&h1;
    ((float2*)p)[f] = raw;
}

// TV-L1 thresholding step.
__device__ __forceinline__ void thresh(
    float gx, float gy, float rho, float grad, float l_t,
    float& v1, float& v2)
{
    float th = l_t * grad;
    if (rho < -th)      { v1 =  l_t * gx; v2 =  l_t * gy; }
    else if (rho > th)  { v1 = -l_t * gx; v2 = -l_t * gy; }
    else                { float s = -rho / grad; v1 = s * gx; v2 = s * gy; }
}

// ---------------------------------------------------------------------------
// S: g2x/g2y (fp16) + rc (fp32) from x,y; iteration-0 u-update (u = v).
// ---------------------------------------------------------------------------
__global__ __launch_bounds__(NTHR) void s_kernel(
    const float* __restrict__ x, const float* __restrict__ y,
    __half* __restrict__ g2x, __half* __restrict__ g2y, float* __restrict__ rc,
    float* __restrict__ u1, float* __restrict__ u2,
    const float* __restrict__ tp, const float* __restrict__ lp)
{
    int f = blockIdx.x * NTHR + threadIdx.x;
    const float l_t = lp[0] * tp[0];

    int idx = f << 2;
    int i  = (idx >> 8) & 255;
    int j0 = idx & 255;

    float4 xc4 = ld4(x, f), yc4 = ld4(y, f);
    const float* xc = (const float*)&xc4;
    const float* yc = (const float*)&yc4;

    float4 a4, b4;                       // wave-uniform row branch
    if (i == 0)            { a4 = ld4(x, f + ROW4); b4 = xc4; }
    else if (i == HH - 1)  { a4 = xc4; b4 = ld4(x, f - ROW4); }
    else                   { a4 = ld4(y, f + ROW4); b4 = ld4(y, f - ROW4); }
    const float* aa = (const float*)&a4;
    const float* bb = (const float*)&b4;

    float yl = (j0 > 0)      ? y[idx - 1] : 0.f;
    float yr = (j0 < WW - 4) ? y[idx + 4] : 0.f;

    float gxo[4], gyo[4], rco[4], u1o[4], u2o[4];
    #pragma unroll
    for (int k = 0; k < 4; ++k) {
        int j = j0 + k;
        float gx;
        if (j == 0)            gx = 0.5f * (xc[1] - xc[0]);
        else if (j == WW - 1)  gx = 0.5f * (xc[3] - xc[2]);
        else {
            float ynext = (k < 3) ? yc[k + 1] : yr;
            float yprev = (k > 0) ? yc[k - 1] : yl;
            gx = 0.5f * (ynext - yprev);
        }
        float gy = 0.5f * (aa[k] - bb[k]);
        // quantize g to fp16 NOW so iteration 0 uses the same values as 1..9
        gx = __half2float(__float2half_rn(gx));
        gy = __half2float(__float2half_rn(gy));
        float rcv = yc[k] - xc[k];
        float grad = gx * gx + gy * gy + EPSF;
        float rho  = rcv + EPSF;
        float v1, v2;
        thresh(gx, gy, rho, grad, l_t, v1, v2);
        gxo[k] = gx; gyo[k] = gy; rco[k] = rcv;
        u1o[k] = v1; u2o[k] = v2;
    }
    st4h(g2x, f, gxo); st4h(g2y, f, gyo); st4(rc, f, rco);
    st4(u1, f, u1o);   st4(u2, f, u2o);
}

// ---------------------------------------------------------------------------
// A: u-update in place. Reads u (own), p (own + left/up halo), g/rc.
// ---------------------------------------------------------------------------
__global__ __launch_bounds__(NTHR) void a_kernel(
    const __half* __restrict__ g2x, const __half* __restrict__ g2y,
    const float* __restrict__ rc,
    float* __restrict__ u1, float* __restrict__ u2,
    const __half* __restrict__ p11, const __half* __restrict__ p12,
    const __half* __restrict__ p21, const __half* __restrict__ p22,
    const float* __restrict__ tp, const float* __restrict__ lp)
{
    int f = blockIdx.x * NTHR + threadIdx.x;
    const float ts  = tp[0];
    const float l_t = lp[0] * ts;

    int idx = f << 2;
    int i  = (idx >> 8) & 255;
    int j0 = idx & 255;

    float gx[4], gy[4], c11[4], c12[4], c21[4], c22[4], up12[4], up22[4];
    ld4h(g2x, f, gx); ld4h(g2y, f, gy);
    ld4h(p11, f, c11); ld4h(p12, f, c12);
    ld4h(p21, f, c21); ld4h(p22, f, c22);
    float4 rc4  = ld4(rc, f);
    float4 u1c4 = ld4(u1, f), u2c4 = ld4(u2, f);
    if (i > 0) { ld4h(p12, f - ROW4, up12); ld4h(p22, f - ROW4, up22); }
    else { up12[0]=up12[1]=up12[2]=up12[3]=0.f;
           up22[0]=up22[1]=up22[2]=up22[3]=0.f; }

    const float* rcv = (const float*)&rc4;
    const float* u1c = (const float*)&u1c4;
    const float* u2c = (const float*)&u2c4;

    float p11l = (j0 > 0) ? __half2float(p11[idx - 1]) : 0.f;
    float p21l = (j0 > 0) ? __half2float(p21[idx - 1]) : 0.f;
    bool notBot = (i < HH - 1);

    float u1o[4], u2o[4];
    #pragma unroll
    for (int k = 0; k < 4; ++k) {
        int j = j0 + k;
        float t11 = (j < WW - 1) ? c11[k] : 0.f;
        float l11 = (k == 0) ? p11l : c11[k - 1];
        float t21 = (j < WW - 1) ? c21[k] : 0.f;
        float l21 = (k == 0) ? p21l : c21[k - 1];
        float t12 = notBot ? c12[k] : 0.f;
        float t22 = notBot ? c22[k] : 0.f;
        float div1 = (t11 - l11) + (t12 - up12[k]);
        float div2 = (t21 - l21) + (t22 - up22[k]);

        float grad = gx[k] * gx[k] + gy[k] * gy[k] + EPSF;
        float rho  = rcv[k] + gx[k] * u1c[k] + gy[k] * u2c[k] + EPSF;
        float v1, v2;
        thresh(gx[k], gy[k], rho, grad, l_t, v1, v2);
        u1o[k] = v1 + u1c[k] + ts * div1;
        u2o[k] = v2 + u2c[k] + ts * div2;
    }
    st4(u1, f, u1o); st4(u2, f, u2o);
}

// ---------------------------------------------------------------------------
// B: p-update in place. Reads p (own), u (own + right/down halo).
// ---------------------------------------------------------------------------
template <bool P0>
__global__ __launch_bounds__(NTHR) void b_kernel(
    const float* __restrict__ u1, const float* __restrict__ u2,
    __half* __restrict__ p11, __half* __restrict__ p12,
    __half* __restrict__ p21, __half* __restrict__ p22,
    const float* __restrict__ tp, const float* __restrict__ ap)
{
    int f = blockIdx.x * NTHR + threadIdx.x;
    const float taut = ap[0] / tp[0];

    int idx = f << 2;
    int i  = (idx >> 8) & 255;
    int j0 = idx & 255;

    float4 u1c4 = ld4(u1, f), u2c4 = ld4(u2, f);
    float4 zero4 = make_float4(0.f, 0.f, 0.f, 0.f);
    bool notBot = (i < HH - 1);
    float4 u1d4 = notBot ? ld4(u1, f + ROW4) : zero4;
    float4 u2d4 = notBot ? ld4(u2, f + ROW4) : zero4;
    float u1r = (j0 < WW - 4) ? u1[idx + 4] : 0.f;
    float u2r = (j0 < WW - 4) ? u2[idx + 4] : 0.f;

    float c11[4], c12[4], c21[4], c22[4];
    if (!P0) {
        ld4h(p11, f, c11); ld4h(p12, f, c12);
        ld4h(p21, f, c21); ld4h(p22, f, c22);
    } else {
        #pragma unroll
        for (int k = 0; k < 4; ++k) { c11[k]=c12[k]=c21[k]=c22[k]=0.f; }
    }

    const float* u1c = (const float*)&u1c4;
    const float* u2c = (const float*)&u2c4;
    const float* u1d = (const float*)&u1d4;
    const float* u2d = (const float*)&u2d4;

    float o11[4], o12[4], o21[4], o22[4];
    #pragma unroll
    for (int k = 0; k < 4; ++k) {
        int j = j0 + k;
        float u1x = 0.f, u2x = 0.f;
        if (j < WW - 1) {
            float n1 = (k < 3) ? u1c[k + 1] : u1r;
            float n2 = (k < 3) ? u2c[k + 1] : u2r;
            u1x = n1 - u1c[k];
            u2x = n2 - u2c[k];
        }
        float u1y = notBot ? (u1d[k] - u1c[k]) : 0.f;
        float u2y = notBot ? (u2d[k] - u2c[k]) : 0.f;

        float n1 = sqrtf(u1x * u1x + u1y * u1y + EPSF);
        float n2 = sqrtf(u2x * u2x + u2y * u2y + EPSF);
        float r1 = 1.f / (1.f + taut * n1);
        float r2 = 1.f / (1.f + taut * n2);
        o11[k] = (c11[k] + taut * u1x) * r1;
        o12[k] = (c12[k] + taut * u1y) * r1;
        o21[k] = (c21[k] + taut * u2x) * r2;
        o22[k] = (c22[k] + taut * u2y) * r2;
    }
    st4h(p11, f, o11); st4h(p12, f, o12);
    st4h(p21, f, o21); st4h(p22, f, o22);
}

// ---------------------------------------------------------------------------
extern "C" void kernel_launch(void* const* d_in, const int* in_sizes, int n_in,
                              void* d_out, int out_size, void* d_ws, size_t ws_size,
                              hipStream_t stream) {
    const float* x = (const float*)d_in[0];
    const float* y = (const float*)d_in[1];
    const float* t = (const float*)d_in[8];
    const float* l = (const float*)d_in[9];
    const float* a = (const float*)d_in[10];

    float* u1 = (float*)d_out;
    float* u2 = u1 + NPIX;

    // ws layout: rc (fp32) then 6 fp16 fields. Total = 16.8 + 6*8.4 = 67 MB.
    char* ws = (char*)d_ws;
    float*  rc  = (float*)ws;
    __half* g2x = (__half*)(ws + (size_t)NPIX * 4);
    __half* g2y = g2x + NPIX;
    __half* p11 = g2y + NPIX;
    __half* p12 = p11 + NPIX;
    __half* p21 = p12 + NPIX;
    __half* p22 = p21 + NPIX;

    dim3 block(NTHR), grid(NBLK);

    // iteration 0
    s_kernel<<<grid, block, 0, stream>>>(x, y, g2x, g2y, rc, u1, u2, t, l);
    b_kernel<true><<<grid, block, 0, stream>>>(u1, u2, p11, p12, p21, p22, t, a);
    // iterations 1..8
    for (int it = 1; it <= 8; ++it) {
        a_kernel<<<grid, block, 0, stream>>>(g2x, g2y, rc, u1, u2,
                                             p11, p12, p21, p22, t, l);
        b_kernel<false><<<grid, block, 0, stream>>>(u1, u2, p11, p12, p21, p22, t, a);
    }
    // iteration 9: p-update is dead, only u-update matters
    a_kernel<<<grid, block, 0, stream>>>(g2x, g2y, rc, u1, u2,
                                         p11, p12, p21, p22, t, l);
}

// Round 6
// 402.619 us; speedup vs baseline: 2.0121x; 1.1691x over previous
//
#include <hip/hip_runtime.h>
#include <hip/hip_fp16.h>

#define HH 256
#define WW 256
#define NB 64
#define NPIX (NB * HH * WW)      // 4,194,304 pixels
#define NF4  (NPIX / 4)          // 1,048,576 groups of 4
#define ROW4 (WW / 4)            // 64 groups per image row
#define EPSF 1e-12f
#define NTHR 256
#define NBLK (NF4 / NTHR)        // 4096 blocks

__device__ __forceinline__ float4 ld4(const float* p, int f) {
    return ((const float4*)p)[f];
}
__device__ __forceinline__ void st4(float* p, int f, const float* v) {
    ((float4*)p)[f] = make_float4(v[0], v[1], v[2], v[3]);
}
__device__ __forceinline__ void ld4h(const __half* p, int f, float* o) {
    float2 raw = ((const float2*)p)[f];
    __half2 h0 = *(__half2*)&raw.x;
    __half2 h1 = *(__half2*)&raw.y;
    float2 a = __half22float2(h0), b = __half22float2(h1);
    o[0] = a.x; o[1] = a.y; o[2] = b.x; o[3] = b.y;
}
__device__ __forceinline__ void st4h(__half* p, int f, const float* v) {
    __half2 h0 = __floats2half2_rn(v[0], v[1]);
    __half2 h1 = __floats2half2_rn(v[2], v[3]);
    float2 raw;
    raw.x = *(float*)&h0; raw.y = *(float*)&h1;
    ((float2*)p)[f] = raw;
}

// TV-L1 thresholding step.
__device__ __forceinline__ void thresh(
    float gx, float gy, float rho, float grad, float l_t,
    float& v1, float& v2)
{
    float th = l_t * grad;
    if (rho < -th)      { v1 =  l_t * gx; v2 =  l_t * gy; }
    else if (rho > th)  { v1 = -l_t * gx; v2 = -l_t * gy; }
    else                { float s = -rho / grad; v1 = s * gx; v2 = s * gy; }
}

// p-pair update at one pixel for one flow: pa=(pao+taut*ux)*r, pb=(pbo+taut*uy)*r
__device__ __forceinline__ void pupd(
    float pao, float pbo, float ux, float uy, float taut,
    float& pa, float& pb)
{
    float n = sqrtf(ux * ux + uy * uy + EPSF);
    float r = 1.f / (1.f + taut * n);
    pa = (pao + taut * ux) * r;
    pb = (pbo + taut * uy) * r;
}

// ---------------------------------------------------------------------------
// S: g2x/g2y (fp16) + rc (fp32) from x,y; iteration-0 u-update (u = v).
// ---------------------------------------------------------------------------
__global__ __launch_bounds__(NTHR) void s_kernel(
    const float* __restrict__ x, const float* __restrict__ y,
    __half* __restrict__ g2x, __half* __restrict__ g2y, float* __restrict__ rc,
    float* __restrict__ u1, float* __restrict__ u2,
    const float* __restrict__ tp, const float* __restrict__ lp)
{
    int f = blockIdx.x * NTHR + threadIdx.x;
    const float l_t = lp[0] * tp[0];

    int idx = f << 2;
    int i  = (idx >> 8) & 255;
    int j0 = idx & 255;

    float4 xc4 = ld4(x, f), yc4 = ld4(y, f);
    const float* xc = (const float*)&xc4;
    const float* yc = (const float*)&yc4;

    float4 a4, b4;                       // wave-uniform row branch
    if (i == 0)            { a4 = ld4(x, f + ROW4); b4 = xc4; }
    else if (i == HH - 1)  { a4 = xc4; b4 = ld4(x, f - ROW4); }
    else                   { a4 = ld4(y, f + ROW4); b4 = ld4(y, f - ROW4); }
    const float* aa = (const float*)&a4;
    const float* bb = (const float*)&b4;

    float yl = (j0 > 0)      ? y[idx - 1] : 0.f;
    float yr = (j0 < WW - 4) ? y[idx + 4] : 0.f;

    float gxo[4], gyo[4], rco[4], u1o[4], u2o[4];
    #pragma unroll
    for (int k = 0; k < 4; ++k) {
        int j = j0 + k;
        float gx;
        if (j == 0)            gx = 0.5f * (xc[1] - xc[0]);
        else if (j == WW - 1)  gx = 0.5f * (xc[3] - xc[2]);
        else {
            float ynext = (k < 3) ? yc[k + 1] : yr;
            float yprev = (k > 0) ? yc[k - 1] : yl;
            gx = 0.5f * (ynext - yprev);
        }
        float gy = 0.5f * (aa[k] - bb[k]);
        // quantize g to fp16 NOW so iteration 0 matches iterations 1..9
        gx = __half2float(__float2half_rn(gx));
        gy = __half2float(__float2half_rn(gy));
        float rcv = yc[k] - xc[k];
        float grad = gx * gx + gy * gy + EPSF;
        float rho  = rcv + EPSF;
        float v1, v2;
        thresh(gx, gy, rho, grad, l_t, v1, v2);
        gxo[k] = gx; gyo[k] = gy; rco[k] = rcv;
        u1o[k] = v1; u2o[k] = v2;
    }
    st4h(g2x, f, gxo); st4h(g2y, f, gyo); st4(rc, f, rco);
    st4(u1, f, u1o);   st4(u2, f, u2o);
}

// ---------------------------------------------------------------------------
// F: fused p-update(it) + u-update(it+1). Pure gather, no LDS, no barriers.
// Each thread computes p_new for its 4 own pixels plus the halo p_new values
// its u-update needs (p11/p21 at the left pixel, p12/p22 at the up row),
// redundantly recomputed from u_old. u and p both ping-pong (in->out).
// P0: p_old == 0. LAST: skip p stores (dead), u_out is the final output.
// ---------------------------------------------------------------------------
template <bool P0, bool LAST>
__global__ __launch_bounds__(NTHR) void f_kernel(
    const __half* __restrict__ g2x, const __half* __restrict__ g2y,
    const float* __restrict__ rc,
    const float* __restrict__ u1i, const float* __restrict__ u2i,
    const __half* __restrict__ p11i, const __half* __restrict__ p12i,
    const __half* __restrict__ p21i, const __half* __restrict__ p22i,
    float* __restrict__ u1o, float* __restrict__ u2o,
    __half* __restrict__ p11o, __half* __restrict__ p12o,
    __half* __restrict__ p21o, __half* __restrict__ p22o,
    const float* __restrict__ tp, const float* __restrict__ lp,
    const float* __restrict__ ap)
{
    int f = blockIdx.x * NTHR + threadIdx.x;
    const float ts   = tp[0];
    const float l_t  = lp[0] * ts;
    const float taut = ap[0] / ts;

    int idx = f << 2;
    int i  = (idx >> 8) & 255;
    int j0 = idx & 255;
    bool hasUp = (i > 0), hasDn = (i < HH - 1);
    bool hasL  = (j0 > 0), hasR = (j0 < WW - 4);

    float4 z4 = make_float4(0.f, 0.f, 0.f, 0.f);

    // --- u_old loads: rows i-1, i, i+1 ---
    float4 u1c4 = ld4(u1i, f),                     u2c4 = ld4(u2i, f);
    float4 u1u4 = hasUp ? ld4(u1i, f - ROW4) : z4, u2u4 = hasUp ? ld4(u2i, f - ROW4) : z4;
    float4 u1d4 = hasDn ? ld4(u1i, f + ROW4) : z4, u2d4 = hasDn ? ld4(u2i, f + ROW4) : z4;
    float u1l  = hasL ? u1i[idx - 1] : 0.f,  u2l  = hasL ? u2i[idx - 1] : 0.f;
    float u1r  = hasR ? u1i[idx + 4] : 0.f,  u2r  = hasR ? u2i[idx + 4] : 0.f;
    float u1ur = (hasUp && hasR) ? u1i[idx - WW + 4] : 0.f;
    float u2ur = (hasUp && hasR) ? u2i[idx - WW + 4] : 0.f;
    float u1dl = (hasDn && hasL) ? u1i[idx + WW - 1] : 0.f;
    float u2dl = (hasDn && hasL) ? u2i[idx + WW - 1] : 0.f;

    const float* u1c = (const float*)&u1c4;
    const float* u2c = (const float*)&u2c4;
    const float* u1u = (const float*)&u1u4;
    const float* u2u = (const float*)&u2u4;
    const float* u1d = (const float*)&u1d4;
    const float* u2d = (const float*)&u2d4;

    // --- p_old loads ---
    float c11[4], c12[4], c21[4], c22[4];        // own
    float p12uo[4], p22uo[4];                    // up row (p12/p22 only)
    float p11lo = 0.f, p21lo = 0.f;              // left pixel (p11/p21 only)
    if (!P0) {
        ld4h(p11i, f, c11); ld4h(p12i, f, c12);
        ld4h(p21i, f, c21); ld4h(p22i, f, c22);
        if (hasUp) { ld4h(p12i, f - ROW4, p12uo); ld4h(p22i, f - ROW4, p22uo); }
        else { p12uo[0]=p12uo[1]=p12uo[2]=p12uo[3]=0.f;
               p22uo[0]=p22uo[1]=p22uo[2]=p22uo[3]=0.f; }
        if (hasL) { p11lo = __half2float(p11i[idx - 1]);
                    p21lo = __half2float(p21i[idx - 1]); }
    } else {
        #pragma unroll
        for (int k = 0; k < 4; ++k) {
            c11[k]=c12[k]=c21[k]=c22[k]=0.f; p12uo[k]=p22uo[k]=0.f;
        }
    }

    // --- p_new: own 4 pixels (all four fields) ---
    float p11n[4], p12n[4], p21n[4], p22n[4];
    #pragma unroll
    for (int k = 0; k < 4; ++k) {
        int j = j0 + k;
        float u1x = (j < WW-1) ? ((k < 3) ? u1c[k+1] : u1r) - u1c[k] : 0.f;
        float u2x = (j < WW-1) ? ((k < 3) ? u2c[k+1] : u2r) - u2c[k] : 0.f;
        float u1y = hasDn ? u1d[k] - u1c[k] : 0.f;
        float u2y = hasDn ? u2d[k] - u2c[k] : 0.f;
        pupd(c11[k], c12[k], u1x, u1y, taut, p11n[k], p12n[k]);
        pupd(c21[k], c22[k], u2x, u2y, taut, p21n[k], p22n[k]);
    }

    // --- p_new halo: left pixel (p11, p21) ---
    float p11nl = 0.f, p21nl = 0.f;
    if (hasL) {
        float u1x = u1c[0] - u1l;                 // j0-1 < WW-1 always
        float u2x = u2c[0] - u2l;
        float u1y = hasDn ? u1dl - u1l : 0.f;
        float u2y = hasDn ? u2dl - u2l : 0.f;
        float d0, d1;
        pupd(p11lo, 0.f, u1x, u1y, taut, p11nl, d0);
        pupd(p21lo, 0.f, u2x, u2y, taut, p21nl, d1);
    }

    // --- p_new halo: up row (p12, p22) ---
    float p12nu[4] = {0.f,0.f,0.f,0.f}, p22nu[4] = {0.f,0.f,0.f,0.f};
    if (hasUp) {
        #pragma unroll
        for (int k = 0; k < 4; ++k) {
            int j = j0 + k;
            float u1x = (j < WW-1) ? ((k < 3) ? u1u[k+1] : u1ur) - u1u[k] : 0.f;
            float u2x = (j < WW-1) ? ((k < 3) ? u2u[k+1] : u2ur) - u2u[k] : 0.f;
            float u1y = u1c[k] - u1u[k];          // i-1 < HH-1 always
            float u2y = u2c[k] - u2u[k];
            float d0, d1;
            pupd(0.f, p12uo[k], u1x, u1y, taut, d0, p12nu[k]);
            pupd(0.f, p22uo[k], u2x, u2y, taut, d1, p22nu[k]);
        }
    }

    // --- u-update with unrounded p_new ---
    float gx[4], gy[4];
    ld4h(g2x, f, gx); ld4h(g2y, f, gy);
    float4 rc4 = ld4(rc, f);
    const float* rcv = (const float*)&rc4;

    float u1n[4], u2n[4];
    #pragma unroll
    for (int k = 0; k < 4; ++k) {
        int j = j0 + k;
        float t11 = (j < WW-1) ? p11n[k] : 0.f;
        float l11 = (k == 0) ? p11nl : p11n[k-1];   // p11nl==0 when !hasL
        float t21 = (j < WW-1) ? p21n[k] : 0.f;
        float l21 = (k == 0) ? p21nl : p21n[k-1];
        float t12 = hasDn ? p12n[k] : 0.f;
        float t22 = hasDn ? p22n[k] : 0.f;
        float div1 = (t11 - l11) + (t12 - p12nu[k]);
        float div2 = (t21 - l21) + (t22 - p22nu[k]);

        float grad = gx[k]*gx[k] + gy[k]*gy[k] + EPSF;
        float rho  = rcv[k] + gx[k]*u1c[k] + gy[k]*u2c[k] + EPSF;
        float v1, v2;
        thresh(gx[k], gy[k], rho, grad, l_t, v1, v2);
        u1n[k] = v1 + u1c[k] + ts * div1;
        u2n[k] = v2 + u2c[k] + ts * div2;
    }

    st4(u1o, f, u1n); st4(u2o, f, u2n);
    if (!LAST) {
        st4h(p11o, f, p11n); st4h(p12o, f, p12n);
        st4h(p21o, f, p21n); st4h(p22o, f, p22n);
    }
}

// ---------------------------------------------------------------------------
extern "C" void kernel_launch(void* const* d_in, const int* in_sizes, int n_in,
                              void* d_out, int out_size, void* d_ws, size_t ws_size,
                              hipStream_t stream) {
    const float* x = (const float*)d_in[0];
    const float* y = (const float*)d_in[1];
    const float* t = (const float*)d_in[8];
    const float* l = (const float*)d_in[9];
    const float* a = (const float*)d_in[10];

    float* u1out = (float*)d_out;
    float* u2out = u1out + NPIX;

    // ws layout: rc(f32), uA(2 f32), uB(2 f32), g(2 h), pA(4 h), pB(4 h)
    char* ws = (char*)d_ws;
    float*  rcp_ = (float*)ws;                               ws += (size_t)NPIX * 4;
    float*  u1A  = (float*)ws;                               ws += (size_t)NPIX * 4;
    float*  u2A  = (float*)ws;                               ws += (size_t)NPIX * 4;
    float*  u1B  = (float*)ws;                               ws += (size_t)NPIX * 4;
    float*  u2B  = (float*)ws;                               ws += (size_t)NPIX * 4;
    __half* g2x  = (__half*)ws;                              ws += (size_t)NPIX * 2;
    __half* g2y  = (__half*)ws;                              ws += (size_t)NPIX * 2;
    __half* p11A = (__half*)ws;                              ws += (size_t)NPIX * 2;
    __half* p12A = (__half*)ws;                              ws += (size_t)NPIX * 2;
    __half* p21A = (__half*)ws;                              ws += (size_t)NPIX * 2;
    __half* p22A = (__half*)ws;                              ws += (size_t)NPIX * 2;
    __half* p11B = (__half*)ws;                              ws += (size_t)NPIX * 2;
    __half* p12B = (__half*)ws;                              ws += (size_t)NPIX * 2;
    __half* p21B = (__half*)ws;                              ws += (size_t)NPIX * 2;
    __half* p22B = (__half*)ws;

    dim3 block(NTHR), grid(NBLK);

    // S: g, rc, u0 -> uA
    s_kernel<<<grid, block, 0, stream>>>(x, y, g2x, g2y, rcp_, u1A, u2A, t, l);

    // F1: (B0 with p=0, A1). uA->uB, p->pA
    f_kernel<true, false><<<grid, block, 0, stream>>>(
        g2x, g2y, rcp_, u1A, u2A,
        p11A, p12A, p21A, p22A,       // unused (P0)
        u1B, u2B, p11A, p12A, p21A, p22A, t, l, a);

    // F2..F8: alternate. u: B->A->B..., p: A->B->A...
    const float* u1s[2] = {u1A, u1B};
    const float* u2s[2] = {u2A, u2B};
    __half* p11s[2] = {p11A, p11B};
    __half* p12s[2] = {p12A, p12B};
    __half* p21s[2] = {p21A, p21B};
    __half* p22s[2] = {p22A, p22B};
    for (int k = 2; k <= 8; ++k) {
        int ui = (k & 1) ? 0 : 1;     // u_in:  k even -> B(1), k odd -> A(0)
        int pi = (k & 1) ? 1 : 0;     // p_in:  k even -> A(0), k odd -> B(1)
        f_kernel<false, false><<<grid, block, 0, stream>>>(
            g2x, g2y, rcp_, u1s[ui], u2s[ui],
            p11s[pi], p12s[pi], p21s[pi], p22s[pi],
            (float*)u1s[1 - ui], (float*)u2s[1 - ui],
            p11s[1 - pi], p12s[1 - pi], p21s[1 - pi], p22s[1 - pi], t, l, a);
    }

    // F9: u_in = F8's out (uA), p_in = F8's out (pB); write d_out, no p store.
    f_kernel<false, true><<<grid, block, 0, stream>>>(
        g2x, g2y, rcp_, u1A, u2A,
        p11B, p12B, p21B, p22B,
        u1out, u2out, p11A, p12A, p21A, p22A, t, l, a);
}